// Round 7
// baseline (1139.372 us; speedup 1.0000x reference)
//
#include <hip/hip_runtime.h>
#include <hip/hip_fp16.h>

// GCN encoder: out = A @ ( relu(A @ (X W1)) W2 ),  A = COO scatter (dst <- src)
// N=100000 nodes, E=1600000 edges, F_IN=128, H1=64, H2=32, all f32.
//
// Round 7: round-6 structure with two fixes:
//  (a) LDS accumulation uses unsafeAtomicAdd -> native ds_add_f32 (plain
//      atomicAdd on shared float = CAS loop; caused the 705us bucket1),
//  (b) accumulator rows padded (stride 65/33 dwords) so atomic phase and
//      strided epilogue reads are bank-conflict-free.

constexpr int N_NODES = 100000;
constexpr int N_EDGES = 1600000;
constexpr int F_IN = 128;
constexpr int H1 = 64;
constexpr int H2 = 32;
constexpr int BSHIFT = 9;                         // 512 nodes per bucket
constexpr int BNODES = 1 << BSHIFT;
constexpr int NBUCK = (N_NODES + BNODES - 1) / BNODES;  // 196
constexpr int CAP = 10240;                        // per-bucket staging capacity
                                                  // (mean 8192, sigma~90 -> 22 sigma)
constexpr int CHUNK = 2048;                       // edges per pass1 workgroup
constexpr int P1_WGS = (N_EDGES + CHUNK - 1) / CHUNK;  // 782
constexpr int GEMM_WGS = (N_NODES + 255) / 256;        // 391
constexpr int TILE_N = 16;                        // W1 column tile (8KB LDS)
constexpr int S1 = H1 + 1;                        // padded acc stride, layer 1
constexpr int S2 = H2 + 1;                        // padded acc stride, layer 2

// ---------------- cursor init: cursor[b] = b*CAP ---------------------------
__global__ __launch_bounds__(256) void init_cursors(int* __restrict__ cursor)
{
    int t = threadIdx.x;
    if (t < NBUCK) cursor[t] = t * CAP;
}

// ---- pass1: bin edges by dst>>9 into fixed-capacity staging (+ gemm1) -----
// staging record: .x = src | (dst_low9 << 17)   (src < 2^17), .y = w bits
__global__ __launch_bounds__(256) void pass1_bin_gemm1(
    const int* __restrict__ src, const int* __restrict__ dst,
    const float* __restrict__ w, int* __restrict__ cursor,
    int2* __restrict__ staging,
    const float* __restrict__ X, const float* __restrict__ W1,
    __half* __restrict__ xw1out)
{
    __shared__ float smem[F_IN * TILE_N];            // 8 KiB (both roles)

    if (blockIdx.x >= P1_WGS) {
        // ---------------- gemm_xw1 role (tiled W1, fp16 out) ----------------
        int row = (blockIdx.x - P1_WGS) * 256 + threadIdx.x;
        bool alive = row < N_NODES;
        const float4* xr = alive
            ? reinterpret_cast<const float4*>(X + (size_t)row * F_IN) : nullptr;
        __half2* oh = alive
            ? reinterpret_cast<__half2*>(xw1out + (size_t)row * H1) : nullptr;

        for (int t = 0; t < H1 / TILE_N; ++t) {
            for (int i = threadIdx.x; i < F_IN * TILE_N; i += 256) {
                int k = i >> 4, j = i & 15;
                smem[i] = W1[(size_t)k * H1 + t * TILE_N + j];
            }
            __syncthreads();
            if (alive) {
                float4 acc[TILE_N / 4];
#pragma unroll
                for (int j = 0; j < TILE_N / 4; ++j)
                    acc[j] = make_float4(0.f, 0.f, 0.f, 0.f);
                for (int k4 = 0; k4 < F_IN / 4; ++k4) {
                    float4 xv = xr[k4];
#pragma unroll
                    for (int kk = 0; kk < 4; ++kk) {
                        float xk = (kk == 0) ? xv.x : (kk == 1) ? xv.y
                                 : (kk == 2) ? xv.z : xv.w;
                        const float4* wr = reinterpret_cast<const float4*>(
                            &smem[(k4 * 4 + kk) * TILE_N]);
#pragma unroll
                        for (int j = 0; j < TILE_N / 4; ++j) {
                            float4 wv = wr[j];
                            acc[j].x += xk * wv.x;
                            acc[j].y += xk * wv.y;
                            acc[j].z += xk * wv.z;
                            acc[j].w += xk * wv.w;
                        }
                    }
                }
#pragma unroll
                for (int j = 0; j < TILE_N / 4; ++j) {
                    oh[t * (TILE_N / 2) + j * 2 + 0] =
                        __floats2half2_rn(acc[j].x, acc[j].y);
                    oh[t * (TILE_N / 2) + j * 2 + 1] =
                        __floats2half2_rn(acc[j].z, acc[j].w);
                }
            }
            __syncthreads();
        }
        return;
    }

    // ---------------- binning role ----------------
    int* lcnt  = (int*)smem;        // [256] counters, then reused as cursors
    int* lbase = lcnt + 256;        // [256] reserved global bases

    int e0 = blockIdx.x * CHUNK;
    int nhere = N_EDGES - e0; if (nhere > CHUNK) nhere = CHUNK;

    lcnt[threadIdx.x] = 0;
    __syncthreads();

    int   es[CHUNK / 256];
    int   ed[CHUNK / 256];
    float ew[CHUNK / 256];
#pragma unroll
    for (int k = 0; k < CHUNK / 256; ++k) {
        int local = k * 256 + threadIdx.x;
        bool v = local < nhere;
        int idx = e0 + local;
        es[k] = v ? src[idx] : 0;
        ed[k] = v ? dst[idx] : -1;
        ew[k] = v ? w[idx] : 0.f;
        if (v) atomicAdd(&lcnt[ed[k] >> BSHIFT], 1);
    }
    __syncthreads();
    if (threadIdx.x < NBUCK) {
        int c = lcnt[threadIdx.x];
        lbase[threadIdx.x] = (c > 0) ? atomicAdd(&cursor[threadIdx.x], c) : 0;
    }
    __syncthreads();
    lcnt[threadIdx.x] = 0;                            // reuse as cursors
    __syncthreads();
#pragma unroll
    for (int k = 0; k < CHUNK / 256; ++k) {
        if (ed[k] >= 0) {
            int b = ed[k] >> BSHIFT;
            int r = atomicAdd(&lcnt[b], 1);
            int pos = lbase[b] + r;
            if (pos < (b + 1) * CAP)                  // capacity guard
                staging[pos] = make_int2(
                    es[k] | ((ed[k] & (BNODES - 1)) << 17),
                    __float_as_int(ew[k]));
        }
    }
}

// ---- layer 1: per-bucket LDS-accumulate SpMM + fused relu + W2 GEMM -------
// acc: 512 x stride-65 f32 = 130KB LDS (padded: banks (node+lane)%32);
// w2s: 8KB. One block per bucket, ds_add_f32 via unsafeAtomicAdd.
__global__ __launch_bounds__(1024) void spmm_bucket1(
    const int* __restrict__ cursor, const int2* __restrict__ staging,
    const __half* __restrict__ xw1h, const float* __restrict__ W2,
    __half* __restrict__ h1w2h)
{
    __shared__ float acc[BNODES * S1];                // 130 KiB
    __shared__ float w2s[H1 * H2];                    // 8 KiB

    int b = blockIdx.x;
    int t = threadIdx.x;
    for (int i = t; i < H1 * H2; i += 1024) w2s[i] = W2[i];
    for (int i = t; i < BNODES * S1; i += 1024) acc[i] = 0.f;
    __syncthreads();

    int base = b * CAP;
    int cnt = cursor[b] - base;
    int wid = t >> 6, lane = t & 63;                  // 16 waves, lane = feature

    int i = wid;
    for (; i + 48 < cnt; i += 64) {                   // 4 edges per wave per iter
        int2 c0 = staging[base + i];
        int2 c1 = staging[base + i + 16];
        int2 c2 = staging[base + i + 32];
        int2 c3 = staging[base + i + 48];
        float v0 = __int_as_float(c0.y) *
                   __half2float(xw1h[(size_t)(c0.x & 0x1FFFF) * H1 + lane]);
        float v1 = __int_as_float(c1.y) *
                   __half2float(xw1h[(size_t)(c1.x & 0x1FFFF) * H1 + lane]);
        float v2 = __int_as_float(c2.y) *
                   __half2float(xw1h[(size_t)(c2.x & 0x1FFFF) * H1 + lane]);
        float v3 = __int_as_float(c3.y) *
                   __half2float(xw1h[(size_t)(c3.x & 0x1FFFF) * H1 + lane]);
        unsafeAtomicAdd(&acc[((c0.x >> 17) & (BNODES - 1)) * S1 + lane], v0);
        unsafeAtomicAdd(&acc[((c1.x >> 17) & (BNODES - 1)) * S1 + lane], v1);
        unsafeAtomicAdd(&acc[((c2.x >> 17) & (BNODES - 1)) * S1 + lane], v2);
        unsafeAtomicAdd(&acc[((c3.x >> 17) & (BNODES - 1)) * S1 + lane], v3);
    }
    for (; i < cnt; i += 16) {
        int2 c = staging[base + i];
        unsafeAtomicAdd(&acc[((c.x >> 17) & (BNODES - 1)) * S1 + lane],
                        __int_as_float(c.y) *
                        __half2float(xw1h[(size_t)(c.x & 0x1FFFF) * H1 + lane]));
    }
    __syncthreads();

    // relu(acc) @ W2 -> h1w2h (fp16). thread -> (row r, col half cb)
    int r = t >> 1;
    int cb = (t & 1) * 16;
    int node = (b << BSHIFT) + r;
    if (node < N_NODES) {
        float o[16];
#pragma unroll
        for (int j = 0; j < 16; ++j) o[j] = 0.f;
        for (int k = 0; k < H1; ++k) {
            float a = fmaxf(acc[r * S1 + k], 0.f);   // bank (r+k)%32: conflict-free
            const float* wr = &w2s[k * H2 + cb];
#pragma unroll
            for (int j = 0; j < 16; ++j) o[j] += a * wr[j];
        }
        __half2* oh = reinterpret_cast<__half2*>(h1w2h + (size_t)node * H2 + cb);
#pragma unroll
        for (int j = 0; j < 8; ++j)
            oh[j] = __floats2half2_rn(o[2 * j], o[2 * j + 1]);
    }
}

// ---- layer 2: per-bucket LDS-accumulate SpMM -> out (f32) -----------------
// acc: 512 x stride-33 f32 = 66KB LDS. Half-wave (32 lanes) per edge.
__global__ __launch_bounds__(1024) void spmm_bucket2(
    const int* __restrict__ cursor, const int2* __restrict__ staging,
    const __half* __restrict__ h1w2h, float* __restrict__ out)
{
    __shared__ float acc[BNODES * S2];                // 66 KiB

    int b = blockIdx.x;
    int t = threadIdx.x;
    for (int i = t; i < BNODES * S2; i += 1024) acc[i] = 0.f;
    __syncthreads();

    int base = b * CAP;
    int cnt = cursor[b] - base;
    int hw = t >> 5, f = t & 31;                      // 32 half-waves, f = feature

    int i = hw;
    for (; i + 96 < cnt; i += 128) {                  // 4 edges per half-wave
        int2 c0 = staging[base + i];
        int2 c1 = staging[base + i + 32];
        int2 c2 = staging[base + i + 64];
        int2 c3 = staging[base + i + 96];
        float v0 = __int_as_float(c0.y) *
                   __half2float(h1w2h[(size_t)(c0.x & 0x1FFFF) * H2 + f]);
        float v1 = __int_as_float(c1.y) *
                   __half2float(h1w2h[(size_t)(c1.x & 0x1FFFF) * H2 + f]);
        float v2 = __int_as_float(c2.y) *
                   __half2float(h1w2h[(size_t)(c2.x & 0x1FFFF) * H2 + f]);
        float v3 = __int_as_float(c3.y) *
                   __half2float(h1w2h[(size_t)(c3.x & 0x1FFFF) * H2 + f]);
        unsafeAtomicAdd(&acc[((c0.x >> 17) & (BNODES - 1)) * S2 + f], v0);
        unsafeAtomicAdd(&acc[((c1.x >> 17) & (BNODES - 1)) * S2 + f], v1);
        unsafeAtomicAdd(&acc[((c2.x >> 17) & (BNODES - 1)) * S2 + f], v2);
        unsafeAtomicAdd(&acc[((c3.x >> 17) & (BNODES - 1)) * S2 + f], v3);
    }
    for (; i < cnt; i += 32) {
        int2 c = staging[base + i];
        unsafeAtomicAdd(&acc[((c.x >> 17) & (BNODES - 1)) * S2 + f],
                        __int_as_float(c.y) *
                        __half2float(h1w2h[(size_t)(c.x & 0x1FFFF) * H2 + f]));
    }
    __syncthreads();

    // write out rows of this bucket (coalesced stores, padded LDS reads)
    int nvalid = N_NODES - (b << BSHIFT);
    if (nvalid > BNODES) nvalid = BNODES;
    size_t gbase = (size_t)(b << BSHIFT) * H2;
    for (int i = t; i < nvalid * H2; i += 1024) {
        int r = i >> 5, j = i & 31;
        out[gbase + i] = acc[r * S2 + j];
    }
}

extern "C" void kernel_launch(void* const* d_in, const int* in_sizes, int n_in,
                              void* d_out, int out_size, void* d_ws, size_t ws_size,
                              hipStream_t stream)
{
    const float* features    = (const float*)d_in[0];   // [N, 128]
    const float* edge_weight = (const float*)d_in[1];   // [E]
    const float* W1          = (const float*)d_in[2];   // [128, 64]
    const float* W2          = (const float*)d_in[3];   // [64, 32]
    const int*   src         = (const int*)d_in[4];     // [E]
    const int*   dst         = (const int*)d_in[5];     // [E]
    float* out = (float*)d_out;                          // [N, 32]

    // workspace layout (~35.3 MB)
    char* p = (char*)d_ws;
    __half* xw1h   = (__half*)p;    p += (size_t)N_NODES * H1 * 2;        // 12.8MB
    __half* h1w2h  = (__half*)p;    p += (size_t)N_NODES * H2 * 2;        // 6.4MB
    int2*  staging = (int2*)p;      p += (size_t)NBUCK * CAP * 8;         // 16.05MB
    int*   cursor  = (int*)p;       p += 256 * 4;

    init_cursors<<<1, 256, 0, stream>>>(cursor);
    pass1_bin_gemm1<<<P1_WGS + GEMM_WGS, 256, 0, stream>>>(
        src, dst, edge_weight, cursor, staging, features, W1, xw1h);
    spmm_bucket1<<<NBUCK, 1024, 0, stream>>>(cursor, staging, xw1h, W2, h1w2h);
    spmm_bucket2<<<NBUCK, 1024, 0, stream>>>(cursor, staging, h1w2h, out);
}

// Round 8
// 248.886 us; speedup vs baseline: 4.5779x; 4.5779x over previous
//
#include <hip/hip_runtime.h>
#include <hip/hip_fp16.h>

// GCN encoder: out = A @ ( relu(A @ (X W1)) W2 ),  A = COO scatter (dst <- src)
// N=100000 nodes, E=1600000 edges, F_IN=128, H1=64, H2=32, all f32.
//
// Round 8: bucket staging (r6) + per-bucket LDS counting sort -> global CSR,
// consumed by r5's high-TLP per-node gather kernels (fp16 tables, no atomics).
// The r6/r7 in-LDS accumulation consumers are gone (latency-bound at 3136
// waves); consumers here run 100K waves.

constexpr int N_NODES = 100000;
constexpr int N_EDGES = 1600000;
constexpr int F_IN = 128;
constexpr int H1 = 64;
constexpr int H2 = 32;
constexpr int BSHIFT = 9;                         // 512 nodes per bucket
constexpr int BNODES = 1 << BSHIFT;
constexpr int NBUCK = (N_NODES + BNODES - 1) / BNODES;  // 196
constexpr int CAP = 10240;                        // per-bucket capacity (mean 8163, 23 sigma)
constexpr int CHUNK = 2048;                       // edges per pass1 binning workgroup
constexpr int P1_WGS = (N_EDGES + CHUNK - 1) / CHUNK;  // 782
constexpr int GEMM_WGS = (N_NODES + 255) / 256;        // 391

// ---------------- cursor init: cursor[b] = b*CAP ---------------------------
__global__ __launch_bounds__(256) void init_cursors(int* __restrict__ cursor)
{
    int t = threadIdx.x;
    if (t < NBUCK) cursor[t] = t * CAP;
}

// ---- pass1: bin edges by dst>>9 into fixed-capacity staging (+ gemm1) -----
// staging record: .x = src | (dst_low9 << 17)   (src < 2^17), .y = w bits
// gemm role: full W1 in 32KB LDS (X read exactly once), fp16 output.
__global__ __launch_bounds__(256) void pass1_bin_gemm1(
    const int* __restrict__ src, const int* __restrict__ dst,
    const float* __restrict__ w, int* __restrict__ cursor,
    int2* __restrict__ staging,
    const float* __restrict__ X, const float* __restrict__ W1,
    __half* __restrict__ xw1out)
{
    __shared__ float smem[F_IN * H1];                // 32 KiB (both roles)

    if (blockIdx.x >= P1_WGS) {
        // ---------------- gemm_xw1 role ----------------
        for (int i = threadIdx.x; i < F_IN * H1; i += 256) smem[i] = W1[i];
        __syncthreads();
        int row = (blockIdx.x - P1_WGS) * 256 + threadIdx.x;
        if (row >= N_NODES) return;
        const float4* xr = reinterpret_cast<const float4*>(X + (size_t)row * F_IN);
        float4 acc[H1 / 4];
#pragma unroll
        for (int j = 0; j < H1 / 4; ++j) acc[j] = make_float4(0.f, 0.f, 0.f, 0.f);
        for (int k4 = 0; k4 < F_IN / 4; ++k4) {
            float4 xv = xr[k4];
#pragma unroll
            for (int kk = 0; kk < 4; ++kk) {
                float xk = (kk == 0) ? xv.x : (kk == 1) ? xv.y
                         : (kk == 2) ? xv.z : xv.w;
                const float4* wr = reinterpret_cast<const float4*>(
                    &smem[(k4 * 4 + kk) * H1]);
#pragma unroll
                for (int j = 0; j < H1 / 4; ++j) {
                    float4 wv = wr[j];
                    acc[j].x += xk * wv.x;
                    acc[j].y += xk * wv.y;
                    acc[j].z += xk * wv.z;
                    acc[j].w += xk * wv.w;
                }
            }
        }
        __half2* oh = reinterpret_cast<__half2*>(xw1out + (size_t)row * H1);
#pragma unroll
        for (int j = 0; j < H1 / 4; ++j) {
            oh[j * 2 + 0] = __floats2half2_rn(acc[j].x, acc[j].y);
            oh[j * 2 + 1] = __floats2half2_rn(acc[j].z, acc[j].w);
        }
        return;
    }

    // ---------------- binning role ----------------
    int* lcnt  = (int*)smem;        // [256] counters, then reused as cursors
    int* lbase = lcnt + 256;        // [256] reserved global bases

    int e0 = blockIdx.x * CHUNK;
    int nhere = N_EDGES - e0; if (nhere > CHUNK) nhere = CHUNK;

    lcnt[threadIdx.x] = 0;
    __syncthreads();

    int   es[CHUNK / 256];
    int   ed[CHUNK / 256];
    float ew[CHUNK / 256];
#pragma unroll
    for (int k = 0; k < CHUNK / 256; ++k) {
        int local = k * 256 + threadIdx.x;
        bool v = local < nhere;
        int idx = e0 + local;
        es[k] = v ? src[idx] : 0;
        ed[k] = v ? dst[idx] : -1;
        ew[k] = v ? w[idx] : 0.f;
        if (v) atomicAdd(&lcnt[ed[k] >> BSHIFT], 1);
    }
    __syncthreads();
    if (threadIdx.x < NBUCK) {
        int c = lcnt[threadIdx.x];
        lbase[threadIdx.x] = (c > 0) ? atomicAdd(&cursor[threadIdx.x], c) : 0;
    }
    __syncthreads();
    lcnt[threadIdx.x] = 0;                            // reuse as cursors
    __syncthreads();
#pragma unroll
    for (int k = 0; k < CHUNK / 256; ++k) {
        if (ed[k] >= 0) {
            int b = ed[k] >> BSHIFT;
            int r = atomicAdd(&lcnt[b], 1);
            int pos = lbase[b] + r;
            if (pos < (b + 1) * CAP)                  // capacity guard
                staging[pos] = make_int2(
                    es[k] | ((ed[k] & (BNODES - 1)) << 17),
                    __float_as_int(ew[k]));
        }
    }
}

// ---- sort_bucket: LDS counting sort of one bucket -> csr + seg ------------
// seg[node] = {start, count} into csr[]. csr record: .x = src, .y = w bits.
__global__ __launch_bounds__(1024) void sort_bucket(
    const int* __restrict__ cursor, const int2* __restrict__ staging,
    int2* __restrict__ csr, int2* __restrict__ seg)
{
    __shared__ int  lcnt[BNODES];                    // 2 KiB
    __shared__ int  lofs[BNODES];                    // 2 KiB
    __shared__ int2 sorted[CAP];                     // 80 KiB

    int b = blockIdx.x, t = threadIdx.x;
    int base = b * CAP;
    int cnt = cursor[b] - base; if (cnt > CAP) cnt = CAP;

    if (t < BNODES) lcnt[t] = 0;
    __syncthreads();

    for (int j = t; j < cnt; j += 1024)
        atomicAdd(&lcnt[(staging[base + j].x >> 17) & (BNODES - 1)], 1);
    __syncthreads();

    // Hillis-Steele inclusive scan over 512 counters
    int v = (t < BNODES) ? lcnt[t] : 0;
    if (t < BNODES) lofs[t] = v;
    __syncthreads();
    for (int off = 1; off < BNODES; off <<= 1) {
        int add = (t >= off && t < BNODES) ? lofs[t - off] : 0;
        __syncthreads();
        if (t < BNODES) lofs[t] += add;
        __syncthreads();
    }
    if (t < BNODES) {
        int excl = lofs[t] - v;
        seg[b * BNODES + t] = make_int2(base + excl, v);
        lcnt[t] = excl;                              // running cursors
    }
    __syncthreads();

    for (int j = t; j < cnt; j += 1024) {
        int2 c = staging[base + j];
        int node = (c.x >> 17) & (BNODES - 1);
        int pos = atomicAdd(&lcnt[node], 1);
        sorted[pos] = make_int2(c.x & 0x1FFFF, c.y);
    }
    __syncthreads();

    for (int j = t; j < cnt; j += 1024) csr[base + j] = sorted[j];
}

// ---- layer 1 SpMM: one wave per node, lane = feature; relu fused ----------
__global__ __launch_bounds__(256) void spmm_csr64h(
    const int2* __restrict__ seg, const int2* __restrict__ csr,
    const __half* __restrict__ xin, __half* __restrict__ outh)
{
    int gid = blockIdx.x * 256 + threadIdx.x;        // grid covers N*64 exactly
    int node = gid >> 6;
    int f = gid & 63;
    int2 s = seg[node];
    int e = s.x, end = s.x + s.y;
    float a0 = 0.f, a1 = 0.f, a2 = 0.f, a3 = 0.f;
    for (; e + 4 <= end; e += 4) {
        int2 c0 = csr[e], c1 = csr[e + 1], c2 = csr[e + 2], c3 = csr[e + 3];
        a0 += __int_as_float(c0.y) * __half2float(xin[(size_t)c0.x * H1 + f]);
        a1 += __int_as_float(c1.y) * __half2float(xin[(size_t)c1.x * H1 + f]);
        a2 += __int_as_float(c2.y) * __half2float(xin[(size_t)c2.x * H1 + f]);
        a3 += __int_as_float(c3.y) * __half2float(xin[(size_t)c3.x * H1 + f]);
    }
    for (; e < end; ++e) {
        int2 c = csr[e];
        a0 += __int_as_float(c.y) * __half2float(xin[(size_t)c.x * H1 + f]);
    }
    float r = (a0 + a1) + (a2 + a3);
    outh[(size_t)node * H1 + f] = __float2half(fmaxf(r, 0.f));   // relu here
}

// ------- GEMM2: h1h(fp16, already relu'd) @ W2 -> h1w2h (fp16) -------------
__global__ __launch_bounds__(256) void gemm_h1w2(
    const __half* __restrict__ Hin, const float* __restrict__ W2,
    __half* __restrict__ out)
{
    __shared__ float ws[H1 * H2];                    // 8 KiB
    for (int i = threadIdx.x; i < H1 * H2; i += 256) ws[i] = W2[i];
    __syncthreads();

    int row = blockIdx.x * 256 + threadIdx.x;
    if (row >= N_NODES) return;

    const __half2* xr = reinterpret_cast<const __half2*>(Hin + (size_t)row * H1);
    float4 acc[H2 / 4];
#pragma unroll
    for (int j = 0; j < H2 / 4; ++j) acc[j] = make_float4(0.f, 0.f, 0.f, 0.f);

    for (int k2 = 0; k2 < H1 / 2; ++k2) {
        float2 xv = __half22float2(xr[k2]);
#pragma unroll
        for (int kk = 0; kk < 2; ++kk) {
            float xk = (kk == 0) ? xv.x : xv.y;
            const float4* wr = reinterpret_cast<const float4*>(
                &ws[(k2 * 2 + kk) * H2]);
#pragma unroll
            for (int j = 0; j < H2 / 4; ++j) {
                float4 wv = wr[j];
                acc[j].x += xk * wv.x;
                acc[j].y += xk * wv.y;
                acc[j].z += xk * wv.z;
                acc[j].w += xk * wv.w;
            }
        }
    }
    __half2* oh = reinterpret_cast<__half2*>(out + (size_t)row * H2);
#pragma unroll
    for (int j = 0; j < H2 / 4; ++j) {
        oh[j * 2 + 0] = __floats2half2_rn(acc[j].x, acc[j].y);
        oh[j * 2 + 1] = __floats2half2_rn(acc[j].z, acc[j].w);
    }
}

// ---- layer 2 SpMM: wave per node, half-waves on even/odd edges ------------
__global__ __launch_bounds__(256) void spmm_csr32h(
    const int2* __restrict__ seg, const int2* __restrict__ csr,
    const __half* __restrict__ xin, float* __restrict__ out)
{
    int gid = blockIdx.x * 256 + threadIdx.x;        // grid covers N*64 exactly
    int node = gid >> 6;
    int f = gid & 31;
    int par = (gid >> 5) & 1;
    int2 s = seg[node];
    int start = s.x, end = s.x + s.y;
    float a0 = 0.f, a1 = 0.f;
    int e = start + par;
    for (; e + 3 < end; e += 4) {                    // this parity: e and e+2
        int2 c0 = csr[e], c1 = csr[e + 2];
        a0 += __int_as_float(c0.y) * __half2float(xin[(size_t)c0.x * H2 + f]);
        a1 += __int_as_float(c1.y) * __half2float(xin[(size_t)c1.x * H2 + f]);
    }
    for (; e < end; e += 2) {
        int2 c = csr[e];
        a0 += __int_as_float(c.y) * __half2float(xin[(size_t)c.x * H2 + f]);
    }
    float acc = a0 + a1;
    acc += __shfl_xor(acc, 32);
    if (par == 0) out[(size_t)node * H2 + f] = acc;
}

extern "C" void kernel_launch(void* const* d_in, const int* in_sizes, int n_in,
                              void* d_out, int out_size, void* d_ws, size_t ws_size,
                              hipStream_t stream)
{
    const float* features    = (const float*)d_in[0];   // [N, 128]
    const float* edge_weight = (const float*)d_in[1];   // [E]
    const float* W1          = (const float*)d_in[2];   // [128, 64]
    const float* W2          = (const float*)d_in[3];   // [64, 32]
    const int*   src         = (const int*)d_in[4];     // [E]
    const int*   dst         = (const int*)d_in[5];     // [E]
    float* out = (float*)d_out;                          // [N, 32]

    // workspace layout (~65 MB)
    char* p = (char*)d_ws;
    __half* xw1h   = (__half*)p;    p += (size_t)N_NODES * H1 * 2;        // 12.8MB
    __half* h1h    = (__half*)p;    p += (size_t)N_NODES * H1 * 2;        // 12.8MB
    __half* h1w2h  = (__half*)p;    p += (size_t)N_NODES * H2 * 2;        // 6.4MB
    int2*  staging = (int2*)p;      p += (size_t)NBUCK * CAP * 8;         // 16.06MB
    int2*  csr     = (int2*)p;      p += (size_t)NBUCK * CAP * 8;         // 16.06MB
    int2*  seg     = (int2*)p;      p += (size_t)NBUCK * BNODES * 8;      // 0.80MB
    int*   cursor  = (int*)p;       p += 256 * 4;

    init_cursors<<<1, 256, 0, stream>>>(cursor);
    pass1_bin_gemm1<<<P1_WGS + GEMM_WGS, 256, 0, stream>>>(
        src, dst, edge_weight, cursor, staging, features, W1, xw1h);
    sort_bucket<<<NBUCK, 1024, 0, stream>>>(cursor, staging, csr, seg);

    spmm_csr64h<<<(N_NODES * 64) / 256, 256, 0, stream>>>(seg, csr, xw1h, h1h);
    gemm_h1w2<<<GEMM_WGS, 256, 0, stream>>>(h1h, W2, h1w2h);
    spmm_csr32h<<<(N_NODES * 64) / 256, 256, 0, stream>>>(seg, csr, h1w2h, out);
}

// Round 9
// 220.909 us; speedup vs baseline: 5.1576x; 1.1266x over previous
//
#include <hip/hip_runtime.h>
#include <hip/hip_fp16.h>

// GCN encoder: out = A @ ( relu(A @ (X W1)) W2 ),  A = COO scatter (dst <- src)
// N=100000 nodes, E=1600000 edges, F_IN=128, H1=64, H2=32, all f32.
//
// Round 9: (a) GEMM2 fused into spmm1's epilogue via wave shuffles (h1 never
// leaves registers; gemm_h1w2 kernel + 25.6MB of traffic eliminated);
// (b) pass1 gemm blocks first (tail trim); (c) vectorized COO loads.

constexpr int N_NODES = 100000;
constexpr int N_EDGES = 1600000;
constexpr int F_IN = 128;
constexpr int H1 = 64;
constexpr int H2 = 32;
constexpr int BSHIFT = 9;                         // 512 nodes per bucket
constexpr int BNODES = 1 << BSHIFT;
constexpr int NBUCK = (N_NODES + BNODES - 1) / BNODES;  // 196
constexpr int CAP = 10240;                        // per-bucket capacity (mean 8163)
constexpr int CHUNK = 2048;                       // edges per binning workgroup
constexpr int P1_WGS = (N_EDGES + CHUNK - 1) / CHUNK;  // 782
constexpr int GEMM_WGS = (N_NODES + 255) / 256;        // 391

// ---------------- cursor init: cursor[b] = b*CAP ---------------------------
__global__ __launch_bounds__(256) void init_cursors(int* __restrict__ cursor)
{
    int t = threadIdx.x;
    if (t < NBUCK) cursor[t] = t * CAP;
}

// ---- pass1: gemm1 blocks first, then binning blocks -----------------------
// staging record: .x = src | (dst_low9 << 17)   (src < 2^17), .y = w bits
__global__ __launch_bounds__(256) void pass1_bin_gemm1(
    const int* __restrict__ src, const int* __restrict__ dst,
    const float* __restrict__ w, int* __restrict__ cursor,
    int2* __restrict__ staging,
    const float* __restrict__ X, const float* __restrict__ W1,
    __half* __restrict__ xw1out)
{
    __shared__ float smem[F_IN * H1];                // 32 KiB (both roles)

    if (blockIdx.x < GEMM_WGS) {
        // ---------------- gemm_xw1 role ----------------
        for (int i = threadIdx.x; i < F_IN * H1; i += 256) smem[i] = W1[i];
        __syncthreads();
        int row = blockIdx.x * 256 + threadIdx.x;
        if (row >= N_NODES) return;
        const float4* xr = reinterpret_cast<const float4*>(X + (size_t)row * F_IN);
        float4 acc[H1 / 4];
#pragma unroll
        for (int j = 0; j < H1 / 4; ++j) acc[j] = make_float4(0.f, 0.f, 0.f, 0.f);
        for (int k4 = 0; k4 < F_IN / 4; ++k4) {
            float4 xv = xr[k4];
#pragma unroll
            for (int kk = 0; kk < 4; ++kk) {
                float xk = (kk == 0) ? xv.x : (kk == 1) ? xv.y
                         : (kk == 2) ? xv.z : xv.w;
                const float4* wr = reinterpret_cast<const float4*>(
                    &smem[(k4 * 4 + kk) * H1]);
#pragma unroll
                for (int j = 0; j < H1 / 4; ++j) {
                    float4 wv = wr[j];
                    acc[j].x += xk * wv.x;
                    acc[j].y += xk * wv.y;
                    acc[j].z += xk * wv.z;
                    acc[j].w += xk * wv.w;
                }
            }
        }
        __half2* oh = reinterpret_cast<__half2*>(xw1out + (size_t)row * H1);
#pragma unroll
        for (int j = 0; j < H1 / 4; ++j) {
            oh[j * 2 + 0] = __floats2half2_rn(acc[j].x, acc[j].y);
            oh[j * 2 + 1] = __floats2half2_rn(acc[j].z, acc[j].w);
        }
        return;
    }

    // ---------------- binning role ----------------
    int* lcnt  = (int*)smem;        // [256] counters, then reused as cursors
    int* lbase = lcnt + 256;        // [256] reserved global bases

    int e0 = (blockIdx.x - GEMM_WGS) * CHUNK;
    int nhere = N_EDGES - e0; if (nhere > CHUNK) nhere = CHUNK;   // 2048 or 512

    lcnt[threadIdx.x] = 0;
    __syncthreads();

    // vectorized loads: each thread owns 8 consecutive edges (nhere % 8 == 0)
    int   es[8];
    int   ed[8];
    float ew[8];
    {
        bool v = (threadIdx.x * 8) < nhere;
        int tb = e0 + threadIdx.x * 8;
        int4 s0, s1, d0, d1; float4 w0, w1;
        if (v) {
            const int4* sp = reinterpret_cast<const int4*>(src + tb);
            s0 = sp[0]; s1 = sp[1];
            const int4* dp = reinterpret_cast<const int4*>(dst + tb);
            d0 = dp[0]; d1 = dp[1];
            const float4* wp = reinterpret_cast<const float4*>(w + tb);
            w0 = wp[0]; w1 = wp[1];
            es[0]=s0.x; es[1]=s0.y; es[2]=s0.z; es[3]=s0.w;
            es[4]=s1.x; es[5]=s1.y; es[6]=s1.z; es[7]=s1.w;
            ed[0]=d0.x; ed[1]=d0.y; ed[2]=d0.z; ed[3]=d0.w;
            ed[4]=d1.x; ed[5]=d1.y; ed[6]=d1.z; ed[7]=d1.w;
            ew[0]=w0.x; ew[1]=w0.y; ew[2]=w0.z; ew[3]=w0.w;
            ew[4]=w1.x; ew[5]=w1.y; ew[6]=w1.z; ew[7]=w1.w;
        } else {
#pragma unroll
            for (int k = 0; k < 8; ++k) { es[k]=0; ed[k]=-1; ew[k]=0.f; }
        }
    }
#pragma unroll
    for (int k = 0; k < 8; ++k)
        if (ed[k] >= 0) atomicAdd(&lcnt[ed[k] >> BSHIFT], 1);
    __syncthreads();
    if (threadIdx.x < NBUCK) {
        int c = lcnt[threadIdx.x];
        lbase[threadIdx.x] = (c > 0) ? atomicAdd(&cursor[threadIdx.x], c) : 0;
    }
    __syncthreads();
    lcnt[threadIdx.x] = 0;                            // reuse as cursors
    __syncthreads();
#pragma unroll
    for (int k = 0; k < 8; ++k) {
        if (ed[k] >= 0) {
            int b = ed[k] >> BSHIFT;
            int r = atomicAdd(&lcnt[b], 1);
            int pos = lbase[b] + r;
            if (pos < (b + 1) * CAP)                  // capacity guard
                staging[pos] = make_int2(
                    es[k] | ((ed[k] & (BNODES - 1)) << 17),
                    __float_as_int(ew[k]));
        }
    }
}

// ---- sort_bucket: LDS counting sort of one bucket -> csr + seg ------------
__global__ __launch_bounds__(1024) void sort_bucket(
    const int* __restrict__ cursor, const int2* __restrict__ staging,
    int2* __restrict__ csr, int2* __restrict__ seg)
{
    __shared__ int  lcnt[BNODES];                    // 2 KiB
    __shared__ int  lofs[BNODES];                    // 2 KiB
    __shared__ int2 sorted[CAP];                     // 80 KiB

    int b = blockIdx.x, t = threadIdx.x;
    int base = b * CAP;
    int cnt = cursor[b] - base; if (cnt > CAP) cnt = CAP;

    if (t < BNODES) lcnt[t] = 0;
    __syncthreads();

    for (int j = t; j < cnt; j += 1024)
        atomicAdd(&lcnt[(staging[base + j].x >> 17) & (BNODES - 1)], 1);
    __syncthreads();

    int v = (t < BNODES) ? lcnt[t] : 0;
    if (t < BNODES) lofs[t] = v;
    __syncthreads();
    for (int off = 1; off < BNODES; off <<= 1) {
        int add = (t >= off && t < BNODES) ? lofs[t - off] : 0;
        __syncthreads();
        if (t < BNODES) lofs[t] += add;
        __syncthreads();
    }
    if (t < BNODES) {
        int excl = lofs[t] - v;
        seg[b * BNODES + t] = make_int2(base + excl, v);
        lcnt[t] = excl;                              // running cursors
    }
    __syncthreads();

    for (int j = t; j < cnt; j += 1024) {
        int2 c = staging[base + j];
        int node = (c.x >> 17) & (BNODES - 1);
        int pos = atomicAdd(&lcnt[node], 1);
        sorted[pos] = make_int2(c.x & 0x1FFFF, c.y);
    }
    __syncthreads();

    for (int j = t; j < cnt; j += 1024) csr[base + j] = sorted[j];
}

// ---- layer1 SpMM + fused relu + W2: one wave per node ---------------------
// lane f holds h1[node][f]; epilogue computes (relu(h1) @ W2) in-register via
// shfl broadcasts (half-waves split the k-sum), writes h1w2 fp16 directly.
__global__ __launch_bounds__(256) void spmm1_fused(
    const int2* __restrict__ seg, const int2* __restrict__ csr,
    const __half* __restrict__ xin, const float* __restrict__ W2,
    __half* __restrict__ h1w2h)
{
    __shared__ float w2s[H1 * H2];                   // 8 KiB
    for (int i = threadIdx.x; i < H1 * H2; i += 256) w2s[i] = W2[i];
    __syncthreads();

    int gid = blockIdx.x * 256 + threadIdx.x;        // grid covers N*64 exactly
    int node = gid >> 6;
    int f = gid & 63;
    int2 s = seg[node];
    int e = s.x, end = s.x + s.y;
    float a0 = 0.f, a1 = 0.f, a2 = 0.f, a3 = 0.f;
    for (; e + 4 <= end; e += 4) {
        int2 c0 = csr[e], c1 = csr[e + 1], c2 = csr[e + 2], c3 = csr[e + 3];
        a0 += __int_as_float(c0.y) * __half2float(xin[(size_t)c0.x * H1 + f]);
        a1 += __int_as_float(c1.y) * __half2float(xin[(size_t)c1.x * H1 + f]);
        a2 += __int_as_float(c2.y) * __half2float(xin[(size_t)c2.x * H1 + f]);
        a3 += __int_as_float(c3.y) * __half2float(xin[(size_t)c3.x * H1 + f]);
    }
    for (; e < end; ++e) {
        int2 c = csr[e];
        a0 += __int_as_float(c.y) * __half2float(xin[(size_t)c.x * H1 + f]);
    }
    float r = fmaxf((a0 + a1) + (a2 + a3), 0.f);     // relu(h1[node][f])

    // fused GEMM2: o[j] = sum_k r_k * W2[k][j];  lane (j, half) sums 32 k's
    int j = f & 31;
    int kb = (f >> 5) << 5;                          // 0 or 32
    float o = 0.f;
#pragma unroll
    for (int kk = 0; kk < 32; ++kk) {
        float a = __shfl(r, kb + kk, 64);
        o += a * w2s[(kb + kk) * H2 + j];
    }
    o += __shfl_xor(o, 32, 64);
    if (f < 32)
        h1w2h[(size_t)node * H2 + j] = __float2half(o);
}

// ---- layer 2 SpMM: wave per node, half-waves on even/odd edges ------------
__global__ __launch_bounds__(256) void spmm_csr32h(
    const int2* __restrict__ seg, const int2* __restrict__ csr,
    const __half* __restrict__ xin, float* __restrict__ out)
{
    int gid = blockIdx.x * 256 + threadIdx.x;        // grid covers N*64 exactly
    int node = gid >> 6;
    int f = gid & 31;
    int par = (gid >> 5) & 1;
    int2 s = seg[node];
    int start = s.x, end = s.x + s.y;
    float a0 = 0.f, a1 = 0.f;
    int e = start + par;
    for (; e + 3 < end; e += 4) {                    // this parity: e and e+2
        int2 c0 = csr[e], c1 = csr[e + 2];
        a0 += __int_as_float(c0.y) * __half2float(xin[(size_t)c0.x * H2 + f]);
        a1 += __int_as_float(c1.y) * __half2float(xin[(size_t)c1.x * H2 + f]);
    }
    for (; e < end; e += 2) {
        int2 c = csr[e];
        a0 += __int_as_float(c.y) * __half2float(xin[(size_t)c.x * H2 + f]);
    }
    float acc = a0 + a1;
    acc += __shfl_xor(acc, 32);
    if (par == 0) out[(size_t)node * H2 + f] = acc;
}

extern "C" void kernel_launch(void* const* d_in, const int* in_sizes, int n_in,
                              void* d_out, int out_size, void* d_ws, size_t ws_size,
                              hipStream_t stream)
{
    const float* features    = (const float*)d_in[0];   // [N, 128]
    const float* edge_weight = (const float*)d_in[1];   // [E]
    const float* W1          = (const float*)d_in[2];   // [128, 64]
    const float* W2          = (const float*)d_in[3];   // [64, 32]
    const int*   src         = (const int*)d_in[4];     // [E]
    const int*   dst         = (const int*)d_in[5];     // [E]
    float* out = (float*)d_out;                          // [N, 32]

    // workspace layout (~52 MB)
    char* p = (char*)d_ws;
    __half* xw1h   = (__half*)p;    p += (size_t)N_NODES * H1 * 2;        // 12.8MB
    __half* h1w2h  = (__half*)p;    p += (size_t)N_NODES * H2 * 2;        // 6.4MB
    int2*  staging = (int2*)p;      p += (size_t)NBUCK * CAP * 8;         // 16.06MB
    int2*  csr     = (int2*)p;      p += (size_t)NBUCK * CAP * 8;         // 16.06MB
    int2*  seg     = (int2*)p;      p += (size_t)NBUCK * BNODES * 8;      // 0.80MB
    int*   cursor  = (int*)p;       p += 256 * 4;

    init_cursors<<<1, 256, 0, stream>>>(cursor);
    pass1_bin_gemm1<<<P1_WGS + GEMM_WGS, 256, 0, stream>>>(
        src, dst, edge_weight, cursor, staging, features, W1, xw1h);
    sort_bucket<<<NBUCK, 1024, 0, stream>>>(cursor, staging, csr, seg);

    spmm1_fused<<<(N_NODES * 64) / 256, 256, 0, stream>>>(seg, csr, xw1h, W2, h1w2h);
    spmm_csr32h<<<(N_NODES * 64) / 256, 256, 0, stream>>>(seg, csr, h1w2h, out);
}

// Round 10
// 189.721 us; speedup vs baseline: 6.0055x; 1.1644x over previous
//
#include <hip/hip_runtime.h>
#include <hip/hip_fp16.h>

// GCN encoder: out = A @ ( relu(A @ (X W1)) W2 ),  A = COO scatter (dst <- src)
// N=100000 nodes, E=1600000 edges, F_IN=128, H1=64, H2=32, all f32.
//
// Round 10: half2 gathers (feature-pair per lane, wave halves/quarters split
// edges) in both SpMM consumers + W2 preloaded into registers (epilogue is
// 32 shfl + 32 FMA, no LDS). Rest identical to round 9.

constexpr int N_NODES = 100000;
constexpr int N_EDGES = 1600000;
constexpr int F_IN = 128;
constexpr int H1 = 64;
constexpr int H2 = 32;
constexpr int BSHIFT = 9;                         // 512 nodes per bucket
constexpr int BNODES = 1 << BSHIFT;
constexpr int NBUCK = (N_NODES + BNODES - 1) / BNODES;  // 196
constexpr int CAP = 10240;                        // per-bucket capacity (mean 8163)
constexpr int CHUNK = 2048;                       // edges per binning workgroup
constexpr int P1_WGS = (N_EDGES + CHUNK - 1) / CHUNK;  // 782
constexpr int GEMM_WGS = (N_NODES + 255) / 256;        // 391

// ---------------- cursor init: cursor[b] = b*CAP ---------------------------
__global__ __launch_bounds__(256) void init_cursors(int* __restrict__ cursor)
{
    int t = threadIdx.x;
    if (t < NBUCK) cursor[t] = t * CAP;
}

// ---- pass1: gemm1 blocks first, then binning blocks -----------------------
// staging record: .x = src | (dst_low9 << 17)   (src < 2^17), .y = w bits
__global__ __launch_bounds__(256) void pass1_bin_gemm1(
    const int* __restrict__ src, const int* __restrict__ dst,
    const float* __restrict__ w, int* __restrict__ cursor,
    int2* __restrict__ staging,
    const float* __restrict__ X, const float* __restrict__ W1,
    __half* __restrict__ xw1out)
{
    __shared__ float smem[F_IN * H1];                // 32 KiB (both roles)

    if (blockIdx.x < GEMM_WGS) {
        // ---------------- gemm_xw1 role ----------------
        for (int i = threadIdx.x; i < F_IN * H1; i += 256) smem[i] = W1[i];
        __syncthreads();
        int row = blockIdx.x * 256 + threadIdx.x;
        if (row >= N_NODES) return;
        const float4* xr = reinterpret_cast<const float4*>(X + (size_t)row * F_IN);
        float4 acc[H1 / 4];
#pragma unroll
        for (int j = 0; j < H1 / 4; ++j) acc[j] = make_float4(0.f, 0.f, 0.f, 0.f);
        for (int k4 = 0; k4 < F_IN / 4; ++k4) {
            float4 xv = xr[k4];
#pragma unroll
            for (int kk = 0; kk < 4; ++kk) {
                float xk = (kk == 0) ? xv.x : (kk == 1) ? xv.y
                         : (kk == 2) ? xv.z : xv.w;
                const float4* wr = reinterpret_cast<const float4*>(
                    &smem[(k4 * 4 + kk) * H1]);
#pragma unroll
                for (int j = 0; j < H1 / 4; ++j) {
                    float4 wv = wr[j];
                    acc[j].x += xk * wv.x;
                    acc[j].y += xk * wv.y;
                    acc[j].z += xk * wv.z;
                    acc[j].w += xk * wv.w;
                }
            }
        }
        __half2* oh = reinterpret_cast<__half2*>(xw1out + (size_t)row * H1);
#pragma unroll
        for (int j = 0; j < H1 / 4; ++j) {
            oh[j * 2 + 0] = __floats2half2_rn(acc[j].x, acc[j].y);
            oh[j * 2 + 1] = __floats2half2_rn(acc[j].z, acc[j].w);
        }
        return;
    }

    // ---------------- binning role ----------------
    int* lcnt  = (int*)smem;        // [256] counters, then reused as cursors
    int* lbase = lcnt + 256;        // [256] reserved global bases

    int e0 = (blockIdx.x - GEMM_WGS) * CHUNK;
    int nhere = N_EDGES - e0; if (nhere > CHUNK) nhere = CHUNK;   // 2048 or 512

    lcnt[threadIdx.x] = 0;
    __syncthreads();

    // vectorized loads: each thread owns 8 consecutive edges (nhere % 8 == 0)
    int   es[8];
    int   ed[8];
    float ew[8];
    {
        bool v = (threadIdx.x * 8) < nhere;
        int tb = e0 + threadIdx.x * 8;
        int4 s0, s1, d0, d1; float4 w0, w1;
        if (v) {
            const int4* sp = reinterpret_cast<const int4*>(src + tb);
            s0 = sp[0]; s1 = sp[1];
            const int4* dp = reinterpret_cast<const int4*>(dst + tb);
            d0 = dp[0]; d1 = dp[1];
            const float4* wp = reinterpret_cast<const float4*>(w + tb);
            w0 = wp[0]; w1 = wp[1];
            es[0]=s0.x; es[1]=s0.y; es[2]=s0.z; es[3]=s0.w;
            es[4]=s1.x; es[5]=s1.y; es[6]=s1.z; es[7]=s1.w;
            ed[0]=d0.x; ed[1]=d0.y; ed[2]=d0.z; ed[3]=d0.w;
            ed[4]=d1.x; ed[5]=d1.y; ed[6]=d1.z; ed[7]=d1.w;
            ew[0]=w0.x; ew[1]=w0.y; ew[2]=w0.z; ew[3]=w0.w;
            ew[4]=w1.x; ew[5]=w1.y; ew[6]=w1.z; ew[7]=w1.w;
        } else {
#pragma unroll
            for (int k = 0; k < 8; ++k) { es[k]=0; ed[k]=-1; ew[k]=0.f; }
        }
    }
#pragma unroll
    for (int k = 0; k < 8; ++k)
        if (ed[k] >= 0) atomicAdd(&lcnt[ed[k] >> BSHIFT], 1);
    __syncthreads();
    if (threadIdx.x < NBUCK) {
        int c = lcnt[threadIdx.x];
        lbase[threadIdx.x] = (c > 0) ? atomicAdd(&cursor[threadIdx.x], c) : 0;
    }
    __syncthreads();
    lcnt[threadIdx.x] = 0;                            // reuse as cursors
    __syncthreads();
#pragma unroll
    for (int k = 0; k < 8; ++k) {
        if (ed[k] >= 0) {
            int b = ed[k] >> BSHIFT;
            int r = atomicAdd(&lcnt[b], 1);
            int pos = lbase[b] + r;
            if (pos < (b + 1) * CAP)                  // capacity guard
                staging[pos] = make_int2(
                    es[k] | ((ed[k] & (BNODES - 1)) << 17),
                    __float_as_int(ew[k]));
        }
    }
}

// ---- sort_bucket: LDS counting sort of one bucket -> csr + seg ------------
__global__ __launch_bounds__(1024) void sort_bucket(
    const int* __restrict__ cursor, const int2* __restrict__ staging,
    int2* __restrict__ csr, int2* __restrict__ seg)
{
    __shared__ int  lcnt[BNODES];                    // 2 KiB
    __shared__ int  lofs[BNODES];                    // 2 KiB
    __shared__ int2 sorted[CAP];                     // 80 KiB

    int b = blockIdx.x, t = threadIdx.x;
    int base = b * CAP;
    int cnt = cursor[b] - base; if (cnt > CAP) cnt = CAP;

    if (t < BNODES) lcnt[t] = 0;
    __syncthreads();

    for (int j = t; j < cnt; j += 1024)
        atomicAdd(&lcnt[(staging[base + j].x >> 17) & (BNODES - 1)], 1);
    __syncthreads();

    int v = (t < BNODES) ? lcnt[t] : 0;
    if (t < BNODES) lofs[t] = v;
    __syncthreads();
    for (int off = 1; off < BNODES; off <<= 1) {
        int add = (t >= off && t < BNODES) ? lofs[t - off] : 0;
        __syncthreads();
        if (t < BNODES) lofs[t] += add;
        __syncthreads();
    }
    if (t < BNODES) {
        int excl = lofs[t] - v;
        seg[b * BNODES + t] = make_int2(base + excl, v);
        lcnt[t] = excl;                              // running cursors
    }
    __syncthreads();

    for (int j = t; j < cnt; j += 1024) {
        int2 c = staging[base + j];
        int node = (c.x >> 17) & (BNODES - 1);
        int pos = atomicAdd(&lcnt[node], 1);
        sorted[pos] = make_int2(c.x & 0x1FFFF, c.y);
    }
    __syncthreads();

    for (int j = t; j < cnt; j += 1024) csr[base + j] = sorted[j];
}

// ---- layer1 SpMM + fused relu + W2: one wave per node ---------------------
// Lane = (parity, feature-pair): lanes 0-31 even edges, 32-63 odd edges; each
// lane gathers half2 (2 feats). After cross-half combine, epilogue GEMM2 runs
// on registers: W2 column preloaded in 32 VGPRs, 32 shfl + 32 FMA.
__global__ __launch_bounds__(256) void spmm1_fused(
    const int2* __restrict__ seg, const int2* __restrict__ csr,
    const __half* __restrict__ xin, const float* __restrict__ W2,
    __half* __restrict__ h1w2h)
{
    int gid = blockIdx.x * 256 + threadIdx.x;        // grid covers N*64 exactly
    int node = gid >> 6;
    int f = gid & 63;
    int par = f >> 5;                                // edge parity
    int f2 = f & 31;                                 // feature pair: 2f2, 2f2+1

    // preload W2[kb..kb+31][f2] into registers (coalesced, L1/L2-resident)
    float w2r[32];
#pragma unroll
    for (int kk = 0; kk < 32; ++kk)
        w2r[kk] = W2[(par * 32 + kk) * H2 + f2];

    int2 s = seg[node];
    int end = s.x + s.y;
    float2 a0 = make_float2(0.f, 0.f), a1 = make_float2(0.f, 0.f);
    int e = s.x + par;
    for (; e + 2 < end; e += 4) {                    // this parity: e, e+2
        int2 c0 = csr[e], c1 = csr[e + 2];
        float2 x0 = __half22float2(
            *reinterpret_cast<const __half2*>(&xin[(size_t)c0.x * H1 + 2 * f2]));
        float2 x1 = __half22float2(
            *reinterpret_cast<const __half2*>(&xin[(size_t)c1.x * H1 + 2 * f2]));
        float w0 = __int_as_float(c0.y), w1 = __int_as_float(c1.y);
        a0.x += w0 * x0.x; a0.y += w0 * x0.y;
        a1.x += w1 * x1.x; a1.y += w1 * x1.y;
    }
    for (; e < end; e += 2) {
        int2 c = csr[e];
        float2 x = __half22float2(
            *reinterpret_cast<const __half2*>(&xin[(size_t)c.x * H1 + 2 * f2]));
        float wv = __int_as_float(c.y);
        a0.x += wv * x.x; a0.y += wv * x.y;
    }
    float rx = a0.x + a1.x, ry = a0.y + a1.y;
    rx += __shfl_xor(rx, 32, 64);                    // combine parities
    ry += __shfl_xor(ry, 32, 64);
    rx = fmaxf(rx, 0.f); ry = fmaxf(ry, 0.f);        // relu(h1) pair, dup'd halves

    // o[j=f2] partial over k = par*32 + kk; pair p = 16*par + kk/2
    float o = 0.f;
#pragma unroll
    for (int kk = 0; kk < 32; kk += 2) {
        int p = 16 * par + (kk >> 1);
        o += __shfl(rx, p, 64) * w2r[kk];
        o += __shfl(ry, p, 64) * w2r[kk + 1];
    }
    o += __shfl_xor(o, 32, 64);
    if (f < 32)
        h1w2h[(size_t)node * H2 + f2] = __float2half(o);
}

// ---- layer 2 SpMM: wave per node, quarter-waves on edge slots, half2 ------
__global__ __launch_bounds__(256) void spmm_csr32h(
    const int2* __restrict__ seg, const int2* __restrict__ csr,
    const __half* __restrict__ xin, float* __restrict__ out)
{
    int gid = blockIdx.x * 256 + threadIdx.x;        // grid covers N*64 exactly
    int node = gid >> 6;
    int lane = gid & 63;
    int slot = lane >> 4;                            // edge slot 0..3
    int f2 = lane & 15;                              // feature pair: 2f2, 2f2+1

    int2 s = seg[node];
    int end = s.x + s.y;
    float2 a0 = make_float2(0.f, 0.f), a1 = make_float2(0.f, 0.f);
    int e = s.x + slot;
    for (; e + 4 < end; e += 8) {                    // this slot: e, e+4
        int2 c0 = csr[e], c1 = csr[e + 4];
        float2 x0 = __half22float2(
            *reinterpret_cast<const __half2*>(&xin[(size_t)c0.x * H2 + 2 * f2]));
        float2 x1 = __half22float2(
            *reinterpret_cast<const __half2*>(&xin[(size_t)c1.x * H2 + 2 * f2]));
        float w0 = __int_as_float(c0.y), w1 = __int_as_float(c1.y);
        a0.x += w0 * x0.x; a0.y += w0 * x0.y;
        a1.x += w1 * x1.x; a1.y += w1 * x1.y;
    }
    for (; e < end; e += 4) {
        int2 c = csr[e];
        float2 x = __half22float2(
            *reinterpret_cast<const __half2*>(&xin[(size_t)c.x * H2 + 2 * f2]));
        float wv = __int_as_float(c.y);
        a0.x += wv * x.x; a0.y += wv * x.y;
    }
    float ox = a0.x + a1.x, oy = a0.y + a1.y;
    ox += __shfl_xor(ox, 16, 64); oy += __shfl_xor(oy, 16, 64);
    ox += __shfl_xor(ox, 32, 64); oy += __shfl_xor(oy, 32, 64);
    if (lane < 16)
        *reinterpret_cast<float2*>(&out[(size_t)node * H2 + 2 * f2]) =
            make_float2(ox, oy);
}

extern "C" void kernel_launch(void* const* d_in, const int* in_sizes, int n_in,
                              void* d_out, int out_size, void* d_ws, size_t ws_size,
                              hipStream_t stream)
{
    const float* features    = (const float*)d_in[0];   // [N, 128]
    const float* edge_weight = (const float*)d_in[1];   // [E]
    const float* W1          = (const float*)d_in[2];   // [128, 64]
    const float* W2          = (const float*)d_in[3];   // [64, 32]
    const int*   src         = (const int*)d_in[4];     // [E]
    const int*   dst         = (const int*)d_in[5];     // [E]
    float* out = (float*)d_out;                          // [N, 32]

    // workspace layout (~52 MB)
    char* p = (char*)d_ws;
    __half* xw1h   = (__half*)p;    p += (size_t)N_NODES * H1 * 2;        // 12.8MB
    __half* h1w2h  = (__half*)p;    p += (size_t)N_NODES * H2 * 2;        // 6.4MB
    int2*  staging = (int2*)p;      p += (size_t)NBUCK * CAP * 8;         // 16.06MB
    int2*  csr     = (int2*)p;      p += (size_t)NBUCK * CAP * 8;         // 16.06MB
    int2*  seg     = (int2*)p;      p += (size_t)NBUCK * BNODES * 8;      // 0.80MB
    int*   cursor  = (int*)p;       p += 256 * 4;

    init_cursors<<<1, 256, 0, stream>>>(cursor);
    pass1_bin_gemm1<<<P1_WGS + GEMM_WGS, 256, 0, stream>>>(
        src, dst, edge_weight, cursor, staging, features, W1, xw1h);
    sort_bucket<<<NBUCK, 1024, 0, stream>>>(cursor, staging, csr, seg);

    spmm1_fused<<<(N_NODES * 64) / 256, 256, 0, stream>>>(seg, csr, xw1h, W2, h1w2h);
    spmm_csr32h<<<(N_NODES * 64) / 256, 256, 0, stream>>>(seg, csr, h1w2h, out);
}

// Round 11
// 180.420 us; speedup vs baseline: 6.3151x; 1.0516x over previous
//
#include <hip/hip_runtime.h>
#include <hip/hip_fp16.h>

// GCN encoder: out = A @ ( relu(A @ (X W1)) W2 ),  A = COO scatter (dst <- src)
// N=100000 nodes, E=1600000 edges, F_IN=128, H1=64, H2=32, all f32.
//
// Round 11: deepen MLP. spmm1: 4 accum/parity (8 gathers in flight per wave);
// spmm2: 4 accum/slot; pass1 binning: CHUNK 4096 (16 edges/thread, longer
// contiguous staging runs, half the cursor-atomic rounds).

constexpr int N_NODES = 100000;
constexpr int N_EDGES = 1600000;
constexpr int F_IN = 128;
constexpr int H1 = 64;
constexpr int H2 = 32;
constexpr int BSHIFT = 9;                         // 512 nodes per bucket
constexpr int BNODES = 1 << BSHIFT;
constexpr int NBUCK = (N_NODES + BNODES - 1) / BNODES;  // 196
constexpr int CAP = 10240;                        // per-bucket capacity (mean 8163)
constexpr int CHUNK = 4096;                       // edges per binning workgroup
constexpr int P1_WGS = (N_EDGES + CHUNK - 1) / CHUNK;  // 391
constexpr int GEMM_WGS = (N_NODES + 255) / 256;        // 391

// ---------------- cursor init: cursor[b] = b*CAP ---------------------------
__global__ __launch_bounds__(256) void init_cursors(int* __restrict__ cursor)
{
    int t = threadIdx.x;
    if (t < NBUCK) cursor[t] = t * CAP;
}

// ---- pass1: gemm1 blocks first, then binning blocks -----------------------
// staging record: .x = src | (dst_low9 << 17)   (src < 2^17), .y = w bits
__global__ __launch_bounds__(256) void pass1_bin_gemm1(
    const int* __restrict__ src, const int* __restrict__ dst,
    const float* __restrict__ w, int* __restrict__ cursor,
    int2* __restrict__ staging,
    const float* __restrict__ X, const float* __restrict__ W1,
    __half* __restrict__ xw1out)
{
    __shared__ float smem[F_IN * H1];                // 32 KiB (both roles)

    if (blockIdx.x < GEMM_WGS) {
        // ---------------- gemm_xw1 role ----------------
        for (int i = threadIdx.x; i < F_IN * H1; i += 256) smem[i] = W1[i];
        __syncthreads();
        int row = blockIdx.x * 256 + threadIdx.x;
        if (row >= N_NODES) return;
        const float4* xr = reinterpret_cast<const float4*>(X + (size_t)row * F_IN);
        float4 acc[H1 / 4];
#pragma unroll
        for (int j = 0; j < H1 / 4; ++j) acc[j] = make_float4(0.f, 0.f, 0.f, 0.f);
        for (int k4 = 0; k4 < F_IN / 4; ++k4) {
            float4 xv = xr[k4];
#pragma unroll
            for (int kk = 0; kk < 4; ++kk) {
                float xk = (kk == 0) ? xv.x : (kk == 1) ? xv.y
                         : (kk == 2) ? xv.z : xv.w;
                const float4* wr = reinterpret_cast<const float4*>(
                    &smem[(k4 * 4 + kk) * H1]);
#pragma unroll
                for (int j = 0; j < H1 / 4; ++j) {
                    float4 wv = wr[j];
                    acc[j].x += xk * wv.x;
                    acc[j].y += xk * wv.y;
                    acc[j].z += xk * wv.z;
                    acc[j].w += xk * wv.w;
                }
            }
        }
        __half2* oh = reinterpret_cast<__half2*>(xw1out + (size_t)row * H1);
#pragma unroll
        for (int j = 0; j < H1 / 4; ++j) {
            oh[j * 2 + 0] = __floats2half2_rn(acc[j].x, acc[j].y);
            oh[j * 2 + 1] = __floats2half2_rn(acc[j].z, acc[j].w);
        }
        return;
    }

    // ---------------- binning role (16 edges per thread) ----------------
    int* lcnt  = (int*)smem;        // [256] counters, then reused as cursors
    int* lbase = lcnt + 256;        // [256] reserved global bases

    int e0 = (blockIdx.x - GEMM_WGS) * CHUNK;
    int nhere = N_EDGES - e0; if (nhere > CHUNK) nhere = CHUNK;  // 4096 or 2560

    lcnt[threadIdx.x] = 0;
    __syncthreads();

    int   es[16];
    int   ed[16];
    float ew[16];
    {
        bool v = (threadIdx.x * 16) < nhere;         // nhere % 16 == 0
        int tb = e0 + threadIdx.x * 16;
        if (v) {
            const int4* sp = reinterpret_cast<const int4*>(src + tb);
            const int4* dp = reinterpret_cast<const int4*>(dst + tb);
            const float4* wp = reinterpret_cast<const float4*>(w + tb);
#pragma unroll
            for (int q = 0; q < 4; ++q) {
                int4 sv = sp[q], dv = dp[q]; float4 wv = wp[q];
                es[4*q+0]=sv.x; es[4*q+1]=sv.y; es[4*q+2]=sv.z; es[4*q+3]=sv.w;
                ed[4*q+0]=dv.x; ed[4*q+1]=dv.y; ed[4*q+2]=dv.z; ed[4*q+3]=dv.w;
                ew[4*q+0]=wv.x; ew[4*q+1]=wv.y; ew[4*q+2]=wv.z; ew[4*q+3]=wv.w;
            }
        } else {
#pragma unroll
            for (int k = 0; k < 16; ++k) { es[k]=0; ed[k]=-1; ew[k]=0.f; }
        }
    }
#pragma unroll
    for (int k = 0; k < 16; ++k)
        if (ed[k] >= 0) atomicAdd(&lcnt[ed[k] >> BSHIFT], 1);
    __syncthreads();
    if (threadIdx.x < NBUCK) {
        int c = lcnt[threadIdx.x];
        lbase[threadIdx.x] = (c > 0) ? atomicAdd(&cursor[threadIdx.x], c) : 0;
    }
    __syncthreads();
    lcnt[threadIdx.x] = 0;                            // reuse as cursors
    __syncthreads();
#pragma unroll
    for (int k = 0; k < 16; ++k) {
        if (ed[k] >= 0) {
            int b = ed[k] >> BSHIFT;
            int r = atomicAdd(&lcnt[b], 1);
            int pos = lbase[b] + r;
            if (pos < (b + 1) * CAP)                  // capacity guard
                staging[pos] = make_int2(
                    es[k] | ((ed[k] & (BNODES - 1)) << 17),
                    __float_as_int(ew[k]));
        }
    }
}

// ---- sort_bucket: LDS counting sort of one bucket -> csr + seg ------------
__global__ __launch_bounds__(1024) void sort_bucket(
    const int* __restrict__ cursor, const int2* __restrict__ staging,
    int2* __restrict__ csr, int2* __restrict__ seg)
{
    __shared__ int  lcnt[BNODES];                    // 2 KiB
    __shared__ int  lofs[BNODES];                    // 2 KiB
    __shared__ int2 sorted[CAP];                     // 80 KiB

    int b = blockIdx.x, t = threadIdx.x;
    int base = b * CAP;
    int cnt = cursor[b] - base; if (cnt > CAP) cnt = CAP;

    if (t < BNODES) lcnt[t] = 0;
    __syncthreads();

    for (int j = t; j < cnt; j += 1024)
        atomicAdd(&lcnt[(staging[base + j].x >> 17) & (BNODES - 1)], 1);
    __syncthreads();

    int v = (t < BNODES) ? lcnt[t] : 0;
    if (t < BNODES) lofs[t] = v;
    __syncthreads();
    for (int off = 1; off < BNODES; off <<= 1) {
        int add = (t >= off && t < BNODES) ? lofs[t - off] : 0;
        __syncthreads();
        if (t < BNODES) lofs[t] += add;
        __syncthreads();
    }
    if (t < BNODES) {
        int excl = lofs[t] - v;
        seg[b * BNODES + t] = make_int2(base + excl, v);
        lcnt[t] = excl;                              // running cursors
    }
    __syncthreads();

    for (int j = t; j < cnt; j += 1024) {
        int2 c = staging[base + j];
        int node = (c.x >> 17) & (BNODES - 1);
        int pos = atomicAdd(&lcnt[node], 1);
        sorted[pos] = make_int2(c.x & 0x1FFFF, c.y);
    }
    __syncthreads();

    for (int j = t; j < cnt; j += 1024) csr[base + j] = sorted[j];
}

// ---- layer1 SpMM + fused relu + W2: one wave per node ---------------------
// Lanes 0-31 even edges, 32-63 odd edges; lane gathers half2 (2 feats).
// 4 accumulators per parity = 8 gathers in flight per wave.
__global__ __launch_bounds__(256) void spmm1_fused(
    const int2* __restrict__ seg, const int2* __restrict__ csr,
    const __half* __restrict__ xin, const float* __restrict__ W2,
    __half* __restrict__ h1w2h)
{
    int gid = blockIdx.x * 256 + threadIdx.x;        // grid covers N*64 exactly
    int node = gid >> 6;
    int f = gid & 63;
    int par = f >> 5;                                // edge parity
    int f2 = f & 31;                                 // feature pair: 2f2, 2f2+1

    // preload W2[par*32 .. +31][f2] into registers (coalesced, cache-resident)
    float w2r[32];
#pragma unroll
    for (int kk = 0; kk < 32; ++kk)
        w2r[kk] = W2[(par * 32 + kk) * H2 + f2];

    int2 s = seg[node];
    int end = s.x + s.y;
    float2 a0 = make_float2(0.f, 0.f), a1 = make_float2(0.f, 0.f);
    float2 a2 = make_float2(0.f, 0.f), a3 = make_float2(0.f, 0.f);
    int e = s.x + par;
    for (; e + 6 < end; e += 8) {                    // this parity: e,e+2,e+4,e+6
        int2 c0 = csr[e], c1 = csr[e + 2], c2 = csr[e + 4], c3 = csr[e + 6];
        float2 x0 = __half22float2(
            *reinterpret_cast<const __half2*>(&xin[(size_t)c0.x * H1 + 2 * f2]));
        float2 x1 = __half22float2(
            *reinterpret_cast<const __half2*>(&xin[(size_t)c1.x * H1 + 2 * f2]));
        float2 x2 = __half22float2(
            *reinterpret_cast<const __half2*>(&xin[(size_t)c2.x * H1 + 2 * f2]));
        float2 x3 = __half22float2(
            *reinterpret_cast<const __half2*>(&xin[(size_t)c3.x * H1 + 2 * f2]));
        float w0 = __int_as_float(c0.y), w1 = __int_as_float(c1.y);
        float w2v = __int_as_float(c2.y), w3 = __int_as_float(c3.y);
        a0.x += w0 * x0.x; a0.y += w0 * x0.y;
        a1.x += w1 * x1.x; a1.y += w1 * x1.y;
        a2.x += w2v * x2.x; a2.y += w2v * x2.y;
        a3.x += w3 * x3.x; a3.y += w3 * x3.y;
    }
    for (; e < end; e += 2) {
        int2 c = csr[e];
        float2 x = __half22float2(
            *reinterpret_cast<const __half2*>(&xin[(size_t)c.x * H1 + 2 * f2]));
        float wv = __int_as_float(c.y);
        a0.x += wv * x.x; a0.y += wv * x.y;
    }
    float rx = (a0.x + a1.x) + (a2.x + a3.x);
    float ry = (a0.y + a1.y) + (a2.y + a3.y);
    rx += __shfl_xor(rx, 32, 64);                    // combine parities
    ry += __shfl_xor(ry, 32, 64);
    rx = fmaxf(rx, 0.f); ry = fmaxf(ry, 0.f);        // relu(h1) pair, dup'd halves

    // o[j=f2] partial over k = par*32 + kk; pair p = 16*par + kk/2
    float o = 0.f;
#pragma unroll
    for (int kk = 0; kk < 32; kk += 2) {
        int p = 16 * par + (kk >> 1);
        o += __shfl(rx, p, 64) * w2r[kk];
        o += __shfl(ry, p, 64) * w2r[kk + 1];
    }
    o += __shfl_xor(o, 32, 64);
    if (f < 32)
        h1w2h[(size_t)node * H2 + f2] = __float2half(o);
}

// ---- layer 2 SpMM: wave per node, quarter-waves on edge slots, half2 ------
// 4 accumulators per slot = 16 gathers in flight per wave.
__global__ __launch_bounds__(256) void spmm_csr32h(
    const int2* __restrict__ seg, const int2* __restrict__ csr,
    const __half* __restrict__ xin, float* __restrict__ out)
{
    int gid = blockIdx.x * 256 + threadIdx.x;        // grid covers N*64 exactly
    int node = gid >> 6;
    int lane = gid & 63;
    int slot = lane >> 4;                            // edge slot 0..3
    int f2 = lane & 15;                              // feature pair: 2f2, 2f2+1

    int2 s = seg[node];
    int end = s.x + s.y;
    float2 a0 = make_float2(0.f, 0.f), a1 = make_float2(0.f, 0.f);
    float2 a2 = make_float2(0.f, 0.f), a3 = make_float2(0.f, 0.f);
    int e = s.x + slot;
    for (; e + 12 < end; e += 16) {                  // slot: e,e+4,e+8,e+12
        int2 c0 = csr[e], c1 = csr[e + 4], c2 = csr[e + 8], c3 = csr[e + 12];
        float2 x0 = __half22float2(
            *reinterpret_cast<const __half2*>(&xin[(size_t)c0.x * H2 + 2 * f2]));
        float2 x1 = __half22float2(
            *reinterpret_cast<const __half2*>(&xin[(size_t)c1.x * H2 + 2 * f2]));
        float2 x2 = __half22float2(
            *reinterpret_cast<const __half2*>(&xin[(size_t)c2.x * H2 + 2 * f2]));
        float2 x3 = __half22float2(
            *reinterpret_cast<const __half2*>(&xin[(size_t)c3.x * H2 + 2 * f2]));
        float w0 = __int_as_float(c0.y), w1 = __int_as_float(c1.y);
        float w2v = __int_as_float(c2.y), w3 = __int_as_float(c3.y);
        a0.x += w0 * x0.x; a0.y += w0 * x0.y;
        a1.x += w1 * x1.x; a1.y += w1 * x1.y;
        a2.x += w2v * x2.x; a2.y += w2v * x2.y;
        a3.x += w3 * x3.x; a3.y += w3 * x3.y;
    }
    for (; e < end; e += 4) {
        int2 c = csr[e];
        float2 x = __half22float2(
            *reinterpret_cast<const __half2*>(&xin[(size_t)c.x * H2 + 2 * f2]));
        float wv = __int_as_float(c.y);
        a0.x += wv * x.x; a0.y += wv * x.y;
    }
    float ox = (a0.x + a1.x) + (a2.x + a3.x);
    float oy = (a0.y + a1.y) + (a2.y + a3.y);
    ox += __shfl_xor(ox, 16, 64); oy += __shfl_xor(oy, 16, 64);
    ox += __shfl_xor(ox, 32, 64); oy += __shfl_xor(oy, 32, 64);
    if (lane < 16)
        *reinterpret_cast<float2*>(&out[(size_t)node * H2 + 2 * f2]) =
            make_float2(ox, oy);
}

extern "C" void kernel_launch(void* const* d_in, const int* in_sizes, int n_in,
                              void* d_out, int out_size, void* d_ws, size_t ws_size,
                              hipStream_t stream)
{
    const float* features    = (const float*)d_in[0];   // [N, 128]
    const float* edge_weight = (const float*)d_in[1];   // [E]
    const float* W1          = (const float*)d_in[2];   // [128, 64]
    const float* W2          = (const float*)d_in[3];   // [64, 32]
    const int*   src         = (const int*)d_in[4];     // [E]
    const int*   dst         = (const int*)d_in[5];     // [E]
    float* out = (float*)d_out;                          // [N, 32]

    // workspace layout (~52 MB)
    char* p = (char*)d_ws;
    __half* xw1h   = (__half*)p;    p += (size_t)N_NODES * H1 * 2;        // 12.8MB
    __half* h1w2h  = (__half*)p;    p += (size_t)N_NODES * H2 * 2;        // 6.4MB
    int2*  staging = (int2*)p;      p += (size_t)NBUCK * CAP * 8;         // 16.06MB
    int2*  csr     = (int2*)p;      p += (size_t)NBUCK * CAP * 8;         // 16.06MB
    int2*  seg     = (int2*)p;      p += (size_t)NBUCK * BNODES * 8;      // 0.80MB
    int*   cursor  = (int*)p;       p += 256 * 4;

    init_cursors<<<1, 256, 0, stream>>>(cursor);
    pass1_bin_gemm1<<<P1_WGS + GEMM_WGS, 256, 0, stream>>>(
        src, dst, edge_weight, cursor, staging, features, W1, xw1h);
    sort_bucket<<<NBUCK, 1024, 0, stream>>>(cursor, staging, csr, seg);

    spmm1_fused<<<(N_NODES * 64) / 256, 256, 0, stream>>>(seg, csr, xw1h, W2, h1w2h);
    spmm_csr32h<<<(N_NODES * 64) / 256, 256, 0, stream>>>(seg, csr, h1w2h, out);
}